// Round 5
// baseline (24945.749 us; speedup 1.0000x reference)
//
#include <hip/hip_runtime.h>
#include <hip/hip_bf16.h>

typedef __bf16 bf16_t;
typedef bf16_t bfx8 __attribute__((ext_vector_type(8)));
typedef float  fx4  __attribute__((ext_vector_type(4)));

#define TT     256
#define BB     512
#define INDIM  512
#define NGENRE 5
#define HD     2048
#define LATD   1024
#define LATM   1019
#define XK     517
#define XKP    576

// ---------------- helpers ----------------
__device__ __forceinline__ bf16_t f2b(float f) {
  unsigned u = __builtin_bit_cast(unsigned, f);
  u += 0x7fffu + ((u >> 16) & 1u);
  unsigned short s = (unsigned short)(u >> 16);
  return __builtin_bit_cast(bf16_t, s);
}
__device__ __forceinline__ float sigmoidf_(float x) { return 1.0f / (1.0f + __expf(-x)); }

__device__ __forceinline__ void gload16(const bf16_t* g, bf16_t* l) {
  __builtin_amdgcn_global_load_lds((const __attribute__((address_space(1))) void*)g,
                                   (__attribute__((address_space(3))) void*)l,
                                   16, 0, 0);
}
__device__ __forceinline__ void wait_vm0()  { asm volatile("s_waitcnt vmcnt(0)" ::: "memory"); }
__device__ __forceinline__ void wait_vm4()  { asm volatile("s_waitcnt vmcnt(4)" ::: "memory"); }
__device__ __forceinline__ void wait_vm10() { asm volatile("s_waitcnt vmcnt(10)" ::: "memory"); }
__device__ __forceinline__ void wait_vm20() { asm volatile("s_waitcnt vmcnt(20)" ::: "memory"); }
__device__ __forceinline__ void wait_lgkm0() { asm volatile("s_waitcnt lgkmcnt(0)" ::: "memory"); }

// ---------------- fp32 -> bf16 cast with row/col zero-padding ----------------
__global__ void wcast_pad(const float* __restrict__ src, bf16_t* __restrict__ dst,
                          int rows_src, int rows_pad, int K, int ldp) {
  for (int r = blockIdx.x; r < rows_pad; r += gridDim.x)
    for (int c = threadIdx.x; c < ldp; c += 256)
      dst[(size_t)r * ldp + c] = (r < rows_src && c < K) ? f2b(src[(size_t)r * K + c]) : f2b(0.0f);
}

// ---------------- fused GRU step v4b: fat waves, depth-3 counted pipeline ----
// Block: 64 rows x 32 j-cols (x3 gates), 128 thr (2 waves).
// Wave wv owns 64 rows x 16 j-cols x 3 gates -> 24 MFMA : 14 ds_read per K64.
// Staging per wave per stage: 4 A + 6 B = 10 gload16. Depth-3 => 30 in flight;
// waits vmcnt(20)/(10)/(0) drain exactly one tile. LDS 3x(8KB+12KB)=60KB.
// acc slots: 0=r 1=z 2=inn(phase0) 3=hn(phase1)
__global__ __launch_bounds__(128, 2)
void gru4(const bf16_t* __restrict__ A1, int lda1, int k1s,
          const bf16_t* __restrict__ Wih, int ldwih,
          const bf16_t* __restrict__ Hb,
          const bf16_t* __restrict__ Whh,
          const float* __restrict__ Hin,
          const float* __restrict__ bih, const float* __restrict__ bhh,
          float* __restrict__ Hout, bf16_t* __restrict__ HoutB)
{
  __shared__ bf16_t aT[3][64 * 64];
  __shared__ bf16_t bT[3][96 * 64];
  const int tid = threadIdx.x, wv = tid >> 6, lane = tid & 63;
  const int m0 = (blockIdx.x >> 6) * 64;
  const int j0 = (blockIdx.x & 63) * 32;
  const int lr = lane & 15, lk = lane >> 4;
  const int rl = lane >> 3;          // 0..7
  const int cl = (lane & 7) * 8;     // chunk within 64-col row

  fx4 acc[4][4];   // [mfrag][slot]
#pragma unroll
  for (int m = 0; m < 4; ++m)
#pragma unroll
    for (int g = 0; g < 4; ++g) acc[m][g] = fx4{0.f, 0.f, 0.f, 0.f};

  const bf16_t* A1b = A1 ? A1 : Hb;   // dummy base when phase0 absent

  // ---- staging offsets: A = 8 row-groups total (4/wave), B = 12 total (6/wave)
  int aOff0[4], aOff1[4], aSlot[4];
#pragma unroll
  for (int i = 0; i < 4; ++i) {
    const int t = wv * 4 + i;            // 0..7
    const int r = t * 8 + rl;            // 0..63
    const int c = cl ^ ((r & 7) * 8);
    aOff0[i] = (m0 + r) * lda1 + c;
    aOff1[i] = (m0 + r) * HD + c;
    aSlot[i] = t * 512;
  }
  int bOff0[6], bOff1[6], bSlot[6];
#pragma unroll
  for (int i = 0; i < 6; ++i) {
    const int t = wv * 6 + i;            // 0..11
    const int r = t * 8 + rl;            // 0..95
    const int g = r >> 5, jj = r & 31;
    const int c = cl ^ ((r & 7) * 8);
    bOff0[i] = (g * HD + j0 + jj) * ldwih + c;
    bOff1[i] = (g * HD + j0 + jj) * HD + c;
    bSlot[i] = t * 512;                  // <= 11*512 + 511 = 6143 (in-bounds)
  }
  // ---- fragment read offsets (swizzled) ----
  int aRow[4], bRow[3], ko[2];
#pragma unroll
  for (int m = 0; m < 4; ++m) aRow[m] = (m * 16 + lr) * 64;
#pragma unroll
  for (int g = 0; g < 3; ++g) bRow[g] = (g * 32 + wv * 16 + lr) * 64;
#pragma unroll
  for (int h = 0; h < 2; ++h) ko[h] = (h * 32 + lk * 8) ^ ((lr & 7) * 8);

  auto stage = [&](int buf, int s) {
    const bool p = (s >= k1s);
    const int kb = (p ? (s - k1s) : s) * 64;
    bf16_t* aD = &aT[buf][0];
    bf16_t* bD = &bT[buf][0];
    if (p) {
#pragma unroll
      for (int i = 0; i < 4; ++i) gload16(Hb + aOff1[i] + kb, aD + aSlot[i]);
#pragma unroll
      for (int i = 0; i < 6; ++i) gload16(Whh + bOff1[i] + kb, bD + bSlot[i]);
    } else {
#pragma unroll
      for (int i = 0; i < 4; ++i) gload16(A1b + aOff0[i] + kb, aD + aSlot[i]);
#pragma unroll
      for (int i = 0; i < 6; ++i) gload16(Wih + bOff0[i] + kb, bD + bSlot[i]);
    }
  };

  const int nk = k1s + HD / 64;          // >= 32 always
  stage(0, 0); stage(1, 1); stage(2, 2);
  int buf = 0;
  for (int s = 0; s < nk; ++s) {
    const int rem = nk - 1 - s;
    if (rem >= 2) wait_vm20();
    else if (rem == 1) wait_vm10();
    else wait_vm0();
    __builtin_amdgcn_s_barrier();        // tile s resident (all waves' loads)
    const bf16_t* aB = &aT[buf][0];
    const bf16_t* bB = &bT[buf][0];
    bfx8 af[4][2], bfr[3][2];
#pragma unroll
    for (int m = 0; m < 4; ++m)
#pragma unroll
      for (int h = 0; h < 2; ++h)
        af[m][h] = *reinterpret_cast<const bfx8*>(&aB[aRow[m] + ko[h]]);
#pragma unroll
    for (int g = 0; g < 3; ++g)
#pragma unroll
      for (int h = 0; h < 2; ++h)
        bfr[g][h] = *reinterpret_cast<const bfx8*>(&bB[bRow[g] + ko[h]]);
    wait_lgkm0();
    __builtin_amdgcn_sched_barrier(0);
    __builtin_amdgcn_s_barrier();        // all waves done reading buf
    if (s + 3 < nk) stage(buf, s + 3);   // refill the just-freed buffer
    const bool p = (s >= k1s);
    __builtin_amdgcn_s_setprio(1);
#pragma unroll
    for (int h = 0; h < 2; ++h)
#pragma unroll
      for (int g = 0; g < 3; ++g) {
        const int slot = (g == 2) ? (p ? 3 : 2) : g;
#pragma unroll
        for (int m = 0; m < 4; ++m)
          acc[m][slot] = __builtin_amdgcn_mfma_f32_16x16x32_bf16(af[m][h], bfr[g][h], acc[m][slot], 0, 0, 0);
      }
    __builtin_amdgcn_s_setprio(0);
    buf = (buf == 2) ? 0 : buf + 1;
  }

  // ---- epilogue: gates + h update (wave covers 64 rows x 16 cols) ----
  const int col = j0 + wv * 16 + lr;
  const float br  = bih[col] + bhh[col];
  const float bz  = bih[HD + col] + bhh[HD + col];
  const float bin = bih[2 * HD + col];
  const float bhn = bhh[2 * HD + col];
#pragma unroll
  for (int m = 0; m < 4; ++m) {
    const int rbase = m0 + m * 16 + lk * 4;
#pragma unroll
    for (int q = 0; q < 4; ++q) {
      const int row = rbase + q;
      const float r = sigmoidf_(acc[m][0][q] + br);
      const float z = sigmoidf_(acc[m][1][q] + bz);
      const float n = tanhf(acc[m][2][q] + bin + r * (acc[m][3][q] + bhn));
      const float hv = (1.0f - z) * n + z * Hin[(size_t)row * HD + col];
      Hout[(size_t)row * HD + col]  = hv;
      HoutB[(size_t)row * HD + col] = f2b(hv);
    }
  }
}

// ---------------- bf16 NT GEMM (counted-vmcnt pipeline, depth-2) ----------------
__global__ __launch_bounds__(256, 2)
void gemm_nt3(const bf16_t* __restrict__ A, int lda, int K,
              const bf16_t* __restrict__ W, int ldw,
              const float* __restrict__ bias,
              float* __restrict__ O, int ldo, int N,
              bf16_t* __restrict__ OB, int ldob)
{
  __shared__ bf16_t aT[2][64 * 64];
  __shared__ bf16_t bT[2][64 * 64];
  const int tid = threadIdx.x, wave = tid >> 6, lane = tid & 63;
  const int m0 = blockIdx.y * 64, n0 = blockIdx.x * 64;
  const int wm = wave & 1, wn = wave >> 1;
  const int lr = lane & 15, lk = lane >> 4;
  const int rl = lane >> 3, cl = (lane & 7) * 8;

  fx4 acc[2][2];
#pragma unroll
  for (int a = 0; a < 2; ++a)
#pragma unroll
    for (int b = 0; b < 2; ++b) acc[a][b] = fx4{0.f, 0.f, 0.f, 0.f};

  const bf16_t* pA[2]; const bf16_t* pB[2]; int slot[2];
#pragma unroll
  for (int i = 0; i < 2; ++i) {
    const int t = wave * 2 + i;
    const int r = t * 8 + rl;
    const int c = cl ^ ((r & 7) * 8);
    pA[i] = A + (size_t)(m0 + r) * lda + c;
    pB[i] = W + (size_t)(n0 + r) * ldw + c;
    slot[i] = t * 512;
  }
  int aRow[2], bRow[2], ko[2];
#pragma unroll
  for (int f = 0; f < 2; ++f) {
    aRow[f] = (wm * 32 + f * 16 + lr) * 64;
    bRow[f] = (wn * 32 + f * 16 + lr) * 64;
  }
#pragma unroll
  for (int h = 0; h < 2; ++h) ko[h] = (h * 32 + lk * 8) ^ ((lr & 7) * 8);

  auto stage = [&](int buf, int kb) {
#pragma unroll
    for (int i = 0; i < 2; ++i) {
      gload16(pA[i] + kb, &aT[buf][slot[i]]);
      gload16(pB[i] + kb, &bT[buf][slot[i]]);
    }
  };

  const int nk = K >> 6;
  stage(0, 0);
  stage(1, 64);
  for (int s = 0; s < nk; ++s) {
    if (s == nk - 1) wait_vm0(); else wait_vm4();
    __builtin_amdgcn_s_barrier();
    const bf16_t* aB = &aT[s & 1][0];
    const bf16_t* bB = &bT[s & 1][0];
    bfx8 af[2][2], bfr[2][2];
#pragma unroll
    for (int f = 0; f < 2; ++f)
#pragma unroll
      for (int h = 0; h < 2; ++h) {
        af[f][h]  = *reinterpret_cast<const bfx8*>(&aB[aRow[f] + ko[h]]);
        bfr[f][h] = *reinterpret_cast<const bfx8*>(&bB[bRow[f] + ko[h]]);
      }
    wait_lgkm0();
    __builtin_amdgcn_sched_barrier(0);
    __builtin_amdgcn_s_barrier();
    if (s + 2 < nk) stage(s & 1, (s + 2) << 6);
    __builtin_amdgcn_s_setprio(1);
#pragma unroll
    for (int h = 0; h < 2; ++h)
#pragma unroll
      for (int fm = 0; fm < 2; ++fm)
#pragma unroll
        for (int fj = 0; fj < 2; ++fj)
          acc[fm][fj] = __builtin_amdgcn_mfma_f32_16x16x32_bf16(af[fm][h], bfr[fj][h], acc[fm][fj], 0, 0, 0);
    __builtin_amdgcn_s_setprio(0);
  }

#pragma unroll
  for (int fm = 0; fm < 2; ++fm)
#pragma unroll
    for (int fj = 0; fj < 2; ++fj) {
      const int col = n0 + wn * 32 + fj * 16 + lr;
      if (col < N) {
        const float bb = bias[col];
#pragma unroll
        for (int q = 0; q < 4; ++q) {
          const int row = m0 + wm * 32 + fm * 16 + lk * 4 + q;
          const float v = acc[fm][fj][q] + bb;
          O[(size_t)row * ldo + col] = v;
          if (OB) OB[(size_t)row * ldob + col] = f2b(v);
        }
      }
    }
}

// ---------------- z build (writes bf16) ----------------
__global__ void build_zb(const float* __restrict__ mu, const float* __restrict__ lv,
                         const float* __restrict__ eps, const float* __restrict__ genre,
                         bf16_t* __restrict__ zb) {
  int i = blockIdx.x * 256 + threadIdx.x;
  int b = i >> 10, c = i & 1023;
  float v;
  if (c < LATM) {
    size_t k = (size_t)b * LATM + c;
    v = mu[k] + expf(0.5f * lv[k]) * eps[k];
  } else {
    v = genre[b * NGENRE + (c - LATM)];
  }
  zb[i] = f2b(v);
}

// ================= fp32 fallback =================
__global__ __launch_bounds__(256, 1)
void gru_stepF(const float* __restrict__ A1, int lda1, int K1,
               const float* __restrict__ Wih,
               const float* __restrict__ Hin,
               const float* __restrict__ Whh,
               const float* __restrict__ bih, const float* __restrict__ bhh,
               float* __restrict__ Hout)
{
  __shared__ bf16_t a_lds[128][32];
  __shared__ bf16_t b_lds[96][32];
  const int tid = threadIdx.x, wave = tid >> 6, lane = tid & 63;
  const int m0 = (blockIdx.x >> 6) * 128, j0 = (blockIdx.x & 63) * 32;
  const int lr = lane & 15, lk = lane >> 4;
  fx4 acc[2][2][4];
#pragma unroll
  for (int a = 0; a < 2; ++a)
#pragma unroll
    for (int b = 0; b < 2; ++b)
#pragma unroll
      for (int g = 0; g < 4; ++g) acc[a][b][g] = fx4{0.f, 0.f, 0.f, 0.f};

  for (int ph = 0; ph < 2; ++ph) {
    const float* Ag = ph ? Hin : A1;
    const int lda = ph ? HD : lda1, kLen = ph ? HD : K1;
    const float* W = ph ? Whh : Wih;
    const int nslot = ph ? 3 : 2;
    const int nkk = (kLen + 31) >> 5;
    for (int s = 0; s < nkk; ++s) {
      const int kb = s << 5;
#pragma unroll
      for (int it = 0; it < 16; ++it) {
        int i = tid + it * 256;
        int r = i >> 5, kk = i & 31, gk = kb + kk;
        float v = 0.0f;
        if (Ag && gk < kLen) v = Ag[(size_t)(m0 + r) * lda + gk];
        a_lds[r][kk] = f2b(v);
      }
#pragma unroll
      for (int it = 0; it < 12; ++it) {
        int i = tid + it * 256;
        int r = i >> 5, kk = i & 31, g = r >> 5, jj = r & 31, gk = kb + kk;
        b_lds[r][kk] = (gk < kLen) ? f2b(W[(size_t)(g * HD + j0 + jj) * kLen + gk]) : f2b(0.0f);
      }
      __syncthreads();
      bfx8 af[2];
#pragma unroll
      for (int fm = 0; fm < 2; ++fm)
        af[fm] = *reinterpret_cast<const bfx8*>(&a_lds[wave * 32 + fm * 16 + lr][lk * 8]);
#pragma unroll
      for (int g = 0; g < 3; ++g) {
        const int slot = (g == 2) ? nslot : g;
#pragma unroll
        for (int fj = 0; fj < 2; ++fj) {
          bfx8 bfr = *reinterpret_cast<const bfx8*>(&b_lds[g * 32 + fj * 16 + lr][lk * 8]);
#pragma unroll
          for (int fm = 0; fm < 2; ++fm)
            acc[fm][fj][slot] = __builtin_amdgcn_mfma_f32_16x16x32_bf16(af[fm], bfr, acc[fm][fj][slot], 0, 0, 0);
        }
      }
      __syncthreads();
    }
  }
#pragma unroll
  for (int fj = 0; fj < 2; ++fj) {
    const int col = j0 + fj * 16 + lr;
    const float br = bih[col] + bhh[col];
    const float bz = bih[HD + col] + bhh[HD + col];
    const float bin = bih[2 * HD + col];
    const float bhn = bhh[2 * HD + col];
#pragma unroll
    for (int fm = 0; fm < 2; ++fm) {
      const int rbase = m0 + wave * 32 + fm * 16 + lk * 4;
#pragma unroll
      for (int q = 0; q < 4; ++q) {
        const int row = rbase + q;
        const float r = sigmoidf_(acc[fm][fj][0][q] + br);
        const float z = sigmoidf_(acc[fm][fj][1][q] + bz);
        const float n = tanhf(acc[fm][fj][2][q] + bin + r * (acc[fm][fj][3][q] + bhn));
        Hout[(size_t)row * HD + col] = (1.0f - z) * n + z * Hin[(size_t)row * HD + col];
      }
    }
  }
}

__global__ __launch_bounds__(256, 1)
void gemm_ntF(const float* __restrict__ A, int lda, int K,
              const float* __restrict__ W,
              const float* __restrict__ bias,
              float* __restrict__ O, int ldo, int N)
{
  __shared__ bf16_t a_lds[64][32];
  __shared__ bf16_t b_lds[64][32];
  const int tid = threadIdx.x, wave = tid >> 6, lane = tid & 63;
  const int m0 = blockIdx.y * 64, n0 = blockIdx.x * 64;
  const int wm = (wave & 1) * 32, wn = (wave >> 1) * 32;
  const int lr = lane & 15, lk = lane >> 4;
  fx4 acc[2][2];
#pragma unroll
  for (int a = 0; a < 2; ++a)
#pragma unroll
    for (int b = 0; b < 2; ++b) acc[a][b] = fx4{0.f, 0.f, 0.f, 0.f};
  for (int kb = 0; kb < K; kb += 32) {
#pragma unroll
    for (int it = 0; it < 8; ++it) {
      int i = tid + it * 256;
      int r = i >> 5, kk = i & 31;
      a_lds[r][kk] = f2b(A[(size_t)(m0 + r) * lda + kb + kk]);
    }
#pragma unroll
    for (int it = 0; it < 8; ++it) {
      int i = tid + it * 256;
      int r = i >> 5, kk = i & 31;
      int n = n0 + r;
      b_lds[r][kk] = (n < N) ? f2b(W[(size_t)n * K + kb + kk]) : f2b(0.0f);
    }
    __syncthreads();
    bfx8 af[2], bfr[2];
#pragma unroll
    for (int f = 0; f < 2; ++f) {
      af[f] = *reinterpret_cast<const bfx8*>(&a_lds[wm + f * 16 + lr][lk * 8]);
      bfr[f] = *reinterpret_cast<const bfx8*>(&b_lds[wn + f * 16 + lr][lk * 8]);
    }
#pragma unroll
    for (int fm = 0; fm < 2; ++fm)
#pragma unroll
      for (int fj = 0; fj < 2; ++fj)
        acc[fm][fj] = __builtin_amdgcn_mfma_f32_16x16x32_bf16(af[fm], bfr[fj], acc[fm][fj], 0, 0, 0);
    __syncthreads();
  }
#pragma unroll
  for (int fm = 0; fm < 2; ++fm)
#pragma unroll
    for (int fj = 0; fj < 2; ++fj) {
      const int col = n0 + wn + fj * 16 + lr;
      if (col < N) {
        const float bb = bias[col];
#pragma unroll
        for (int q = 0; q < 4; ++q) {
          const int row = m0 + wm + fm * 16 + lk * 4 + q;
          O[(size_t)row * ldo + col] = acc[fm][fj][q] + bb;
        }
      }
    }
}

__global__ void build_zf(const float* __restrict__ mu, const float* __restrict__ lv,
                         const float* __restrict__ eps, const float* __restrict__ genre,
                         float* __restrict__ z) {
  int i = blockIdx.x * 256 + threadIdx.x;
  int b = i >> 10, c = i & 1023;
  z[i] = (c < LATM) ? mu[(size_t)b * LATM + c] + expf(0.5f * lv[(size_t)b * LATM + c]) * eps[(size_t)b * LATM + c]
                    : genre[b * NGENRE + (c - LATM)];
}

// ---------------- host ----------------
extern "C" void kernel_launch(void* const* d_in, const int* in_sizes, int n_in,
                              void* d_out, int out_size, void* d_ws, size_t ws_size,
                              hipStream_t stream) {
  const float* x      = (const float*)d_in[0];
  const float* genre  = (const float*)d_in[1];
  const float* eps    = (const float*)d_in[2];
  const float* eWih   = (const float*)d_in[3];
  const float* eWhh   = (const float*)d_in[4];
  const float* eBih   = (const float*)d_in[5];
  const float* eBhh   = (const float*)d_in[6];
  const float* dWih   = (const float*)d_in[7];
  const float* dWhh   = (const float*)d_in[8];
  const float* dBih   = (const float*)d_in[9];
  const float* dBhh   = (const float*)d_in[10];
  const float* fcMuW  = (const float*)d_in[11];
  const float* fcMuB  = (const float*)d_in[12];
  const float* fcLvW  = (const float*)d_in[13];
  const float* fcLvB  = (const float*)d_in[14];
  const float* fcOutW = (const float*)d_in[15];
  const float* fcOutB = (const float*)d_in[16];
  const float* fcDecW = (const float*)d_in[17];
  const float* fcDecB = (const float*)d_in[18];

  float* out = (float*)d_out;
  float* muO = out + (size_t)TT * BB * INDIM;
  float* lvO = muO + (size_t)BB * LATM;

  const size_t nEih = (size_t)3 * HD * XKP;
  const size_t nEhh = (size_t)3 * HD * HD;
  const size_t nDih = (size_t)3 * HD * INDIM;
  const size_t nDhh = (size_t)3 * HD * HD;
  const size_t nMu  = (size_t)1024 * HD;
  const size_t nOut = (size_t)HD * LATD;
  const size_t nDec = (size_t)INDIM * HD;
  const size_t oEih = 0;
  const size_t oEhh = oEih + nEih;
  const size_t oDih = oEhh + nEhh;
  const size_t oDhh = oDih + nDih;
  const size_t oMu  = oDhh + nDhh;
  const size_t oLv  = oMu + nMu;
  const size_t oOut = oLv + nMu;
  const size_t oDec = oOut + nOut;
  const size_t wTot = oDec + nDec;

  const size_t bytesW  = wTot * 2;
  const size_t bytesHF = (size_t)BB * HD * 4;
  const size_t bytesHB = (size_t)BB * HD * 2;
  const size_t bytesZB = (size_t)BB * LATD * 2;
  const size_t bytesNB = (size_t)BB * INDIM * 2;
  const size_t bytesX1 = (size_t)BB * XKP * 2;
  const size_t bytesXB = (size_t)TT * BB * XKP * 2;
  const size_t needB = bytesW + 2 * bytesHF + 2 * bytesHB + bytesZB + bytesNB + bytesX1 + 1024;
  const size_t needA = needB + bytesXB;

  if (ws_size >= needB) {
    const bool haveXB = (ws_size >= needA);
    char* p = (char*)d_ws;
    bf16_t* wb = (bf16_t*)p;            p += bytesW;
    float* h0  = (float*)p;             p += bytesHF;
    float* h1  = (float*)p;             p += bytesHF;
    bf16_t* hb0 = (bf16_t*)p;           p += bytesHB;
    bf16_t* hb1 = (bf16_t*)p;           p += bytesHB;
    bf16_t* zb  = (bf16_t*)p;           p += bytesZB;
    bf16_t* nb  = (bf16_t*)p;           p += bytesNB;
    bf16_t* x1  = (bf16_t*)p;           p += bytesX1;
    bf16_t* xb  = haveXB ? (bf16_t*)p : nullptr;

    auto cast = [&](const float* s, bf16_t* d, int rs, int rp, int K, int ldp) {
      int g = rp > 8192 ? 8192 : rp;
      wcast_pad<<<g, 256, 0, stream>>>(s, d, rs, rp, K, ldp);
    };
    cast(eWih,   wb + oEih, 3 * HD, 3 * HD, XK,    XKP);
    cast(eWhh,   wb + oEhh, 3 * HD, 3 * HD, HD,    HD);
    cast(dWih,   wb + oDih, 3 * HD, 3 * HD, INDIM, INDIM);
    cast(dWhh,   wb + oDhh, 3 * HD, 3 * HD, HD,    HD);
    cast(fcMuW,  wb + oMu,  LATM,   1024,   HD,    HD);
    cast(fcLvW,  wb + oLv,  LATM,   1024,   HD,    HD);
    cast(fcOutW, wb + oOut, HD,     HD,     LATD,  LATD);
    cast(fcDecW, wb + oDec, INDIM,  INDIM,  HD,    HD);
    if (haveXB) cast(x, xb, TT * BB, TT * BB, XK, XKP);

    hipMemsetAsync(h0, 0, bytesHF, stream);
    hipMemsetAsync(hb0, 0, bytesHB, stream);

    float*  hF[2] = {h0, h1};
    bf16_t* hB[2] = {hb0, hb1};

    // ---- encoder ----
    for (int t = 0; t < TT; ++t) {
      const int ci = t & 1, co = ci ^ 1;
      const bf16_t* xt;
      if (haveXB) {
        xt = xb + (size_t)t * BB * XKP;
      } else {
        wcast_pad<<<512, 256, 0, stream>>>(x + (size_t)t * BB * XK, x1, BB, BB, XK, XKP);
        xt = x1;
      }
      gru4<<<512, 128, 0, stream>>>(xt, XKP, XKP / 64,
                                    wb + oEih, XKP, hB[ci], wb + oEhh,
                                    hF[ci], eBih, eBhh, hF[co], hB[co]);
    }
    // h_enc = hF[0]/hB[0]
    gemm_nt3<<<dim3(16, 8), 256, 0, stream>>>(hB[0], HD, HD, wb + oMu, HD, fcMuB,
                                              muO, LATM, LATM, nullptr, 0);
    gemm_nt3<<<dim3(16, 8), 256, 0, stream>>>(hB[0], HD, HD, wb + oLv, HD, fcLvB,
                                              lvO, LATM, LATM, nullptr, 0);
    build_zb<<<(BB * LATD) / 256, 256, 0, stream>>>(muO, lvO, eps, genre, zb);
    gemm_nt3<<<dim3(32, 8), 256, 0, stream>>>(zb, LATD, LATD, wb + oOut, LATD, fcOutB,
                                              hF[0], HD, HD, hB[0], HD);
    // ---- decoder ----
    for (int t = 0; t < TT; ++t) {
      const int ci = t & 1, co = ci ^ 1;
      gru4<<<512, 128, 0, stream>>>(t ? nb : (const bf16_t*)nullptr, INDIM,
                                    t ? INDIM / 64 : 0,
                                    wb + oDih, INDIM, hB[ci], wb + oDhh,
                                    hF[ci], dBih, dBhh, hF[co], hB[co]);
      gemm_nt3<<<dim3(8, 8), 256, 0, stream>>>(hB[co], HD, HD, wb + oDec, HD, fcDecB,
                                               out + (size_t)t * BB * INDIM, INDIM, INDIM,
                                               nb, INDIM);
    }
  } else {
    // ---- fp32 fallback ----
    float* h0 = (float*)d_ws;
    float* h1 = h0 + (size_t)BB * HD;
    float* zb = h1 + (size_t)BB * HD;
    hipMemsetAsync(h0, 0, (size_t)BB * HD * sizeof(float), stream);
    float* hF[2] = {h0, h1};
    for (int t = 0; t < TT; ++t) {
      const int ci = t & 1, co = ci ^ 1;
      gru_stepF<<<256, 256, 0, stream>>>(x + (size_t)t * BB * XK, XK, XK, eWih,
                                         hF[ci], eWhh, eBih, eBhh, hF[co]);
    }
    gemm_ntF<<<dim3(16, 8), 256, 0, stream>>>(hF[0], HD, HD, fcMuW, fcMuB, muO, LATM, LATM);
    gemm_ntF<<<dim3(16, 8), 256, 0, stream>>>(hF[0], HD, HD, fcLvW, fcLvB, lvO, LATM, LATM);
    build_zf<<<(BB * LATD) / 256, 256, 0, stream>>>(muO, lvO, eps, genre, zb);
    gemm_ntF<<<dim3(32, 8), 256, 0, stream>>>(zb, LATD, LATD, fcOutW, fcOutB, hF[0], HD, HD);
    for (int t = 0; t < TT; ++t) {
      const int ci = t & 1, co = ci ^ 1;
      gru_stepF<<<256, 256, 0, stream>>>(t ? out + (size_t)(t - 1) * BB * INDIM : nullptr,
                                         INDIM, INDIM, dWih, hF[ci], dWhh, dBih, dBhh, hF[co]);
      gemm_ntF<<<dim3(8, 8), 256, 0, stream>>>(hF[co], HD, HD, fcDecW, fcDecB,
                                               out + (size_t)t * BB * INDIM, INDIM, INDIM);
    }
  }
  (void)in_sizes; (void)n_in; (void)out_size;
}